// Round 8
// baseline (235.014 us; speedup 1.0000x reference)
//
#include <hip/hip_runtime.h>
#include <hip/hip_fp16.h>
#include <stdint.h>

// out[b,o] = sum_{l,i} lookups[b,l]*values[b,i]*W[l,i,o] + sum_l lookups[b,l]*bias[l,o]
// GEMM M=65536, K=65 tiles of 64 (i-chunk outer, l inner; tile 64 = bias), N=256.
// fp16 MFMA, 8-phase-style schedule: triple-buffered B, counted vmcnt(4),
// 4 phases x 16 MFMA per K-tile, setprio around clusters.

#define B_TOK 65536
#define L_DIM 16
#define I_DIM 256
#define O_DIM 256
#define BM    256
#define THREADS 512

// LDS: [0,96K) B bufs x3 (pre-swizzled in global, linear gload_lds)
//      [96K,128K) A_chunk [256][64] fp16, XOR-swizzled byte^((row&7)<<4)
//      [128K, +17408) lookups [256][stride 17] f32   -> total 148480 B
#define BOFS(i) ((i) * 32768)
#define AOFF    98304
#define LKOFF   131072
#define LKS     17

typedef __attribute__((ext_vector_type(8))) _Float16 f16x8;
typedef __attribute__((ext_vector_type(4))) float f32x4;
typedef __attribute__((address_space(3))) void      lds_void_t;
typedef const __attribute__((address_space(1))) void gbl_void_t;

#define SBAR  __builtin_amdgcn_s_barrier()
#define SCHED __builtin_amdgcn_sched_barrier(0)

static __device__ __forceinline__ f16x8 scale8(f16x8 a, __half2 s) {
    union { f16x8 v; __half2 h[4]; } u; u.v = a;
#pragma unroll
    for (int q = 0; q < 4; ++q) u.h[q] = __hmul2(u.h[q], s);
    return u.v;
}

// ---------------------------------------------------------------------------
// prep_w: Wst = 65 tiles x 32KB fp16, [o][kk] (B-transposed), pre-swizzled:
// 16B chunk at position cp holds kk-group c = cp ^ (o&7).
// ---------------------------------------------------------------------------
__global__ void prep_w(const float* __restrict__ W, const float* __restrict__ bias,
                       unsigned short* __restrict__ ws) {
    const int t  = blockIdx.x;
    const int o  = blockIdx.y * 32 + (threadIdx.x & 31);
    const int cp = threadIdx.x >> 5;
    const int c  = cp ^ (o & 7);
    uint32_t p[4];
    if (t < 64) {
        const int l = t & 15, ibase = (t >> 4) * 64;
        const float* src = W + ((size_t)l * I_DIM + ibase + c * 8) * O_DIM + o;
#pragma unroll
        for (int jp = 0; jp < 4; ++jp) {
            float a = src[(size_t)(2 * jp) * O_DIM];
            float b = src[(size_t)(2 * jp + 1) * O_DIM];
            p[jp] = __builtin_bit_cast(uint32_t, __floats2half2_rn(a, b));
        }
    } else if (c < 2) {
#pragma unroll
        for (int jp = 0; jp < 4; ++jp) {
            int kk = c * 8 + 2 * jp;
            float a = bias[(size_t)kk * O_DIM + o];
            float b = bias[(size_t)(kk + 1) * O_DIM + o];
            p[jp] = __builtin_bit_cast(uint32_t, __floats2half2_rn(a, b));
        }
    } else {
        p[0] = p[1] = p[2] = p[3] = 0u;
    }
    uint4 q = {p[0], p[1], p[2], p[3]};
    *(uint4*)((char*)ws + (size_t)t * 32768 + o * 128 + cp * 16) = q;
}

// ---------------------------------------------------------------------------
__launch_bounds__(THREADS, 2)
__global__ void md_gemm(const float* __restrict__ lookups,        // [B][16]
                        const float* __restrict__ values,         // [B][256]
                        const unsigned short* __restrict__ Wst,   // [65][16384]
                        float* __restrict__ out) {                // [B][256]
    __shared__ char smem[148480];

    const int tid  = threadIdx.x;
    const int wid  = tid >> 6;
    const int lane = tid & 63;
    const int row0 = blockIdx.x * BM;

    const int r = tid >> 1;          // staging row 0..255
    const int h = tid & 1;           // staging k-half

    const int wm   = wid >> 2;       // 0..1
    const int wn   = wid & 3;        // 0..3
    const int arow = wm * 128 + (lane & 15);
    const int bcol = wn * 64  + (lane & 15);
    const int kkl  = (lane >> 4) * 8;

    float* lkp = (float*)(smem + LKOFF);

    f32x4 acc[8][4];
#pragma unroll
    for (int m = 0; m < 8; ++m)
#pragma unroll
        for (int n = 0; n < 4; ++n) acc[m][n] = (f32x4){0.f, 0.f, 0.f, 0.f};

    // one gload_lds (1KB/wave slice s) of B-tile g into buffer tb
    auto stage1 = [&](int g, int tb, int s) {
        const char* src = (const char*)Wst + (size_t)g * 32768 + wid * 1024
                          + s * 8192 + lane * 16;
        char* dst = smem + BOFS(tb) + wid * 1024 + s * 8192;   // wave-uniform base
        __builtin_amdgcn_global_load_lds((gbl_void_t*)src, (lds_void_t*)dst, 16, 0, 0);
    };

    // stage unscaled fp16 values chunk cc into A-LDS (XOR-swizzled)
    auto stageA = [&](int cc) {
        const float4* vp = (const float4*)(values + (size_t)(row0 + r) * I_DIM
                                           + cc * 64 + h * 32);
        uint32_t p[16];
#pragma unroll
        for (int j = 0; j < 8; ++j) {
            float4 f = vp[j];
            p[2 * j]     = __builtin_bit_cast(uint32_t, __floats2half2_rn(f.x, f.y));
            p[2 * j + 1] = __builtin_bit_cast(uint32_t, __floats2half2_rn(f.z, f.w));
        }
        char* ab = smem + AOFF;
#pragma unroll
        for (int w = 0; w < 4; ++w) {
            uint4 q = {p[4 * w], p[4 * w + 1], p[4 * w + 2], p[4 * w + 3]};
            *(uint4*)(ab + ((r * 128 + h * 64 + w * 16) ^ ((r & 7) << 4))) = q;
        }
    };

    auto stageA_bias = [&]() {    // A = lookups in kk<16, zeros elsewhere
        uint32_t p[16];
#pragma unroll
        for (int j = 0; j < 16; ++j) p[j] = 0u;
        if (h == 0) {
            const float* lr = lkp + r * LKS;
#pragma unroll
            for (int j = 0; j < 8; ++j)
                p[j] = __builtin_bit_cast(uint32_t,
                        __floats2half2_rn(lr[2 * j], lr[2 * j + 1]));
        }
        char* ab = smem + AOFF;
#pragma unroll
        for (int w = 0; w < 4; ++w) {
            uint4 q = {p[4 * w], p[4 * w + 1], p[4 * w + 2], p[4 * w + 3]};
            *(uint4*)(ab + ((r * 128 + h * 64 + w * 16) ^ ((r & 7) << 4))) = q;
        }
    };

    // ---- prologue ----
    {   // lookups -> LDS, stride 17 (odd -> conflict-free), scalar stores
        const float4* lp = (const float4*)(lookups + (size_t)(row0 + r) * L_DIM + h * 8);
        float4 f0 = lp[0], f1 = lp[1];
        float* dst = lkp + r * LKS + h * 8;
        dst[0] = f0.x; dst[1] = f0.y; dst[2] = f0.z; dst[3] = f0.w;
        dst[4] = f1.x; dst[5] = f1.y; dst[6] = f1.z; dst[7] = f1.w;
    }
#pragma unroll
    for (int s = 0; s < 4; ++s) stage1(0, 0, s);
#pragma unroll
    for (int s = 0; s < 4; ++s) stage1(1, 1, s);
    stageA(0);
    __syncthreads();   // full drain: B0,B1 landed; A chunk0 + lookups visible

    f16x8 afk0[8];     // ks0 A-fragments, resident per chunk
#pragma unroll
    for (int mt = 0; mt < 8; ++mt) {
        int row = arow + mt * 16;
        afk0[mt] = *(f16x8*)(smem + AOFF + ((row * 128 + kkl * 2) ^ ((row & 7) << 4)));
    }
    float lknf[8];     // next tile's lookup scales (f32, prefetched)
#pragma unroll
    for (int mt = 0; mt < 8; ++mt) lknf[mt] = lkp[(arow + mt * 16) * LKS];

    int bi = 0;        // buffer holding tile kt
    for (int kt = 0; kt < 64; ++kt) {
        const int  tb       = (kt + 2) % 3;
        const bool boundary = (kt & 15) == 15;
        char* bbase = smem + BOFS(bi);

        __half2 lk2[8];
#pragma unroll
        for (int mt = 0; mt < 8; ++mt) lk2[mt] = __float2half2_rn(lknf[mt]);

        // ---------- P0: read B ks0; gload#0; cluster mt0-3 ks0 ----------
        f16x8 bfr[4];
#pragma unroll
        for (int nt = 0; nt < 4; ++nt) {
            int o = bcol + nt * 16;
            bfr[nt] = *(f16x8*)(bbase + ((o * 128 + kkl * 2) ^ ((o & 7) << 4)));
        }
        if (kt <= 62) stage1(kt + 2, tb, 0);
        SBAR; SCHED;
        __builtin_amdgcn_s_setprio(1);
#pragma unroll
        for (int m = 0; m < 4; ++m) {
            f16x8 a = scale8(afk0[m], lk2[m]);
#pragma unroll
            for (int nt = 0; nt < 4; ++nt)
                acc[m][nt] = __builtin_amdgcn_mfma_f32_16x16x32_f16(a, bfr[nt],
                                                                    acc[m][nt], 0, 0, 0);
        }
        __builtin_amdgcn_s_setprio(0);
        SCHED; SBAR;

        // ---------- P1: read A ks1 mt0-3; gload#1; cluster mt4-7 ks0 ----------
        f16x8 a1lo[4];
#pragma unroll
        for (int m = 0; m < 4; ++m) {
            int row = arow + m * 16;
            a1lo[m] = *(f16x8*)(smem + AOFF
                                + ((row * 128 + 64 + kkl * 2) ^ ((row & 7) << 4)));
        }
        if (kt <= 62) stage1(kt + 2, tb, 1);
        SBAR; SCHED;
        __builtin_amdgcn_s_setprio(1);
#pragma unroll
        for (int m = 4; m < 8; ++m) {
            f16x8 a = scale8(afk0[m], lk2[m]);
#pragma unroll
            for (int nt = 0; nt < 4; ++nt)
                acc[m][nt] = __builtin_amdgcn_mfma_f32_16x16x32_f16(a, bfr[nt],
                                                                    acc[m][nt], 0, 0, 0);
        }
        __builtin_amdgcn_s_setprio(0);
        SCHED; SBAR;

        // ---------- P2: read B ks1 + A ks1 mt4-7; gload#2; cluster mt0-3 ks1 ----------
        f16x8 b2[4];
#pragma unroll
        for (int nt = 0; nt < 4; ++nt) {
            int o = bcol + nt * 16;
            b2[nt] = *(f16x8*)(bbase + ((o * 128 + 64 + kkl * 2) ^ ((o & 7) << 4)));
        }
        f16x8 a1hi[4];
#pragma unroll
        for (int m = 0; m < 4; ++m) {
            int row = arow + (m + 4) * 16;
            a1hi[m] = *(f16x8*)(smem + AOFF
                                + ((row * 128 + 64 + kkl * 2) ^ ((row & 7) << 4)));
        }
        if (kt <= 62) stage1(kt + 2, tb, 2);
        SBAR; SCHED;
        __builtin_amdgcn_s_setprio(1);
#pragma unroll
        for (int m = 0; m < 4; ++m) {
            f16x8 a = scale8(a1lo[m], lk2[m]);
#pragma unroll
            for (int nt = 0; nt < 4; ++nt)
                acc[m][nt] = __builtin_amdgcn_mfma_f32_16x16x32_f16(a, b2[nt],
                                                                    acc[m][nt], 0, 0, 0);
        }
        __builtin_amdgcn_s_setprio(0);
        SCHED; SBAR;

        // ---------- P3: prefetch lk(kt+1); gload#3; cluster mt4-7 ks1 ----------
        {
            int lnx = (kt + 1) & 15;
#pragma unroll
            for (int mt = 0; mt < 8; ++mt)
                lknf[mt] = lkp[(arow + mt * 16) * LKS + lnx];
        }
        if (kt <= 62) stage1(kt + 2, tb, 3);
        SBAR; SCHED;
        __builtin_amdgcn_s_setprio(1);
#pragma unroll
        for (int m = 0; m < 4; ++m) {
            f16x8 a = scale8(a1hi[m], lk2[m + 4]);
#pragma unroll
            for (int nt = 0; nt < 4; ++nt)
                acc[m + 4][nt] = __builtin_amdgcn_mfma_f32_16x16x32_f16(a, b2[nt],
                                                                acc[m + 4][nt], 0, 0, 0);
        }
        __builtin_amdgcn_s_setprio(0);
        SCHED;

        if (!boundary) {
            // counted wait: kt+2's 4 loads stay in flight; kt+1's are done
            asm volatile("s_waitcnt vmcnt(4)" ::: "memory");
            SBAR;
        } else {
            __syncthreads();                 // all waves done with old A chunk
            if (kt < 63) stageA((kt >> 4) + 1); else stageA_bias();
            __syncthreads();                 // new A visible (drains all)
#pragma unroll
            for (int mt = 0; mt < 8; ++mt) { // re-read resident ks0 fragments
                int row = arow + mt * 16;
                afk0[mt] = *(f16x8*)(smem + AOFF
                                     + ((row * 128 + kkl * 2) ^ ((row & 7) << 4)));
            }
        }
        bi = (bi == 2) ? 0 : bi + 1;
    }

    // ---- bias tile kt=64 (buf 64%3==1; only kk<16 nonzero -> ks0 only) ----
    {
        char* bbase = smem + BOFS(1);
        f16x8 bfr[4];
#pragma unroll
        for (int nt = 0; nt < 4; ++nt) {
            int o = bcol + nt * 16;
            bfr[nt] = *(f16x8*)(bbase + ((o * 128 + kkl * 2) ^ ((o & 7) << 4)));
        }
#pragma unroll
        for (int m = 0; m < 8; ++m)
#pragma unroll
            for (int nt = 0; nt < 4; ++nt)
                acc[m][nt] = __builtin_amdgcn_mfma_f32_16x16x32_f16(afk0[m], bfr[nt],
                                                                    acc[m][nt], 0, 0, 0);
    }

    // ---- epilogue: C/D layout col=lane&15, row=(lane>>4)*4+j ----
    const int orow = row0 + wm * 128 + (lane >> 4) * 4;
    const int ocol = wn * 64 + (lane & 15);
#pragma unroll
    for (int mt = 0; mt < 8; ++mt)
#pragma unroll
        for (int nt = 0; nt < 4; ++nt) {
#pragma unroll
            for (int j = 0; j < 4; ++j)
                out[(size_t)(orow + mt * 16 + j) * O_DIM + ocol + nt * 16] = acc[mt][nt][j];
        }
}

extern "C" void kernel_launch(void* const* d_in, const int* in_sizes, int n_in,
                              void* d_out, int out_size, void* d_ws, size_t ws_size,
                              hipStream_t stream) {
    const float* lookups = (const float*)d_in[0];
    const float* values  = (const float*)d_in[1];
    const float* W       = (const float*)d_in[2];
    const float* bias    = (const float*)d_in[3];
    unsigned short* Wst  = (unsigned short*)d_ws;   // 65*32768 B = 2.08 MB

    prep_w<<<dim3(65, 8), dim3(256), 0, stream>>>(W, bias, Wst);
    md_gemm<<<dim3(B_TOK / BM), dim3(THREADS), 0, stream>>>(lookups, values, Wst,
                                                            (float*)d_out);
}